// Round 1
// baseline (1887.128 us; speedup 1.0000x reference)
//
#include <hip/hip_runtime.h>

#define NBLK(n, b) (((n) + (b) - 1) / (b))

// ---------------- graph norm ----------------

__global__ void deg_init_k(float* deg, int n) {
  int i = blockIdx.x * blockDim.x + threadIdx.x;
  if (i < n) deg[i] = 1.0f;  // self-loop
}

__global__ void deg_edge_k(const int* __restrict__ dst, float* deg, int e) {
  int i = blockIdx.x * blockDim.x + threadIdx.x;
  if (i < e) atomicAdd(&deg[dst[i]], 1.0f);
}

__global__ void isq_k(float* deg, int n) {
  int i = blockIdx.x * blockDim.x + threadIdx.x;
  if (i < n) deg[i] = rsqrtf(deg[i]);  // deg >= 1 always
}

__global__ void norm_k(const int* __restrict__ src, const int* __restrict__ dst,
                       const float* __restrict__ isq, float* __restrict__ nrm, int e) {
  int i = blockIdx.x * blockDim.x + threadIdx.x;
  if (i < e) nrm[i] = isq[src[i]] * isq[dst[i]];
}

// ---------------- dense transform (thread-per-row, W in LDS) ----------------
// EPI==1: conv epilogue -> H = acc (for gather), OUT = acc*isq^2 + bias (self loop + bias)
// EPI==0: fc epilogue   -> H = acc + bias

template <int K, int M, bool RELU_IN, int EPI>
__global__ __launch_bounds__(256) void gemm_rows_k(
    const float* __restrict__ X, const float* __restrict__ W,
    const float* __restrict__ bias, const float* __restrict__ isq,
    float* __restrict__ H, float* __restrict__ OUT, int n) {
  __shared__ float Ws[K * M];
  for (int i = threadIdx.x; i < K * M; i += blockDim.x) Ws[i] = W[i];
  __syncthreads();
  int row = blockIdx.x * blockDim.x + threadIdx.x;
  if (row >= n) return;
  float acc[M];
#pragma unroll
  for (int m = 0; m < M; ++m) acc[m] = 0.0f;
  const float* xp = X + (size_t)row * K;
  constexpr int V = (((K * 4) % 16) == 0) ? 4 : 2;  // float4 if 16B-aligned rows, else float2
  for (int k0 = 0; k0 < K; k0 += V) {
    float xv[V];
    if constexpr (V == 4) {
      float4 t = *reinterpret_cast<const float4*>(xp + k0);
      xv[0] = t.x; xv[1] = t.y; xv[2] = t.z; xv[3] = t.w;
    } else {
      float2 t = *reinterpret_cast<const float2*>(xp + k0);
      xv[0] = t.x; xv[1] = t.y;
    }
#pragma unroll
    for (int j = 0; j < V; ++j) {
      float xval = RELU_IN ? fmaxf(xv[j], 0.0f) : xv[j];
      const float* wrow = &Ws[(k0 + j) * M];
#pragma unroll
      for (int m = 0; m < M; ++m) acc[m] += xval * wrow[m];
    }
  }
  size_t base = (size_t)row * M;
  if constexpr (EPI == 1) {
    float s = isq[row];
    s *= s;
#pragma unroll
    for (int m = 0; m < M; ++m) {
      H[base + m] = acc[m];
      OUT[base + m] = acc[m] * s + bias[m];
    }
  } else {
#pragma unroll
    for (int m = 0; m < M; ++m) H[base + m] = acc[m] + bias[m];
  }
}

// ---------------- edge scatter: one wave per edge ----------------

template <int M>
__global__ __launch_bounds__(256) void scatter_k(
    const float* __restrict__ H, const int* __restrict__ src,
    const int* __restrict__ dst, const float* __restrict__ nrm,
    float* __restrict__ OUT, int e) {
  int wid = (int)((blockIdx.x * (size_t)blockDim.x + threadIdx.x) >> 6);
  int lane = threadIdx.x & 63;
  if (wid >= e) return;
  int s = src[wid];
  int d = dst[wid];
  float nv = nrm[wid];
  const float* hp = H + (size_t)s * M;
  float* op = OUT + (size_t)d * M;
#pragma unroll
  for (int c = lane; c < M; c += 64) atomicAdd(op + c, hp[c] * nv);
}

// ---------------- batchnorm ----------------

template <int M, bool RELU_IN>
__global__ __launch_bounds__(256) void bn_stats_k(const float* __restrict__ X,
                                                  float* __restrict__ gsum,
                                                  float* __restrict__ gsq, int total) {
  __shared__ float ssum[M];
  __shared__ float ssq[M];
  for (int c = threadIdx.x; c < M; c += blockDim.x) { ssum[c] = 0.0f; ssq[c] = 0.0f; }
  __syncthreads();
  int stride = gridDim.x * blockDim.x;
  for (int i = blockIdx.x * blockDim.x + threadIdx.x; i < total; i += stride) {
    float v = X[i];
    if (RELU_IN) v = fmaxf(v, 0.0f);
    int c = i % M;
    atomicAdd(&ssum[c], v);
    atomicAdd(&ssq[c], v * v);
  }
  __syncthreads();
  for (int c = threadIdx.x; c < M; c += blockDim.x) {
    atomicAdd(&gsum[c], ssum[c]);
    atomicAdd(&gsq[c], ssq[c]);
  }
}

template <int M>
__global__ void bn_final_k(const float* __restrict__ gsum, const float* __restrict__ gsq,
                           const float* __restrict__ g, const float* __restrict__ b,
                           float* __restrict__ scale, float* __restrict__ shift, float invn) {
  int c = threadIdx.x;
  if (c >= M) return;
  float mu = gsum[c] * invn;
  float var = gsq[c] * invn - mu * mu;
  float r = rsqrtf(var + 1e-5f);
  float sc = g[c] * r;
  scale[c] = sc;
  shift[c] = b[c] - mu * sc;
}

template <int M, bool RELU_IN, bool RELU_OUT>
__global__ __launch_bounds__(256) void bn_apply_k(const float* __restrict__ X,
                                                  const float* __restrict__ scale,
                                                  const float* __restrict__ shift,
                                                  float* __restrict__ Y, int total) {
  int i = blockIdx.x * blockDim.x + threadIdx.x;
  if (i >= total) return;
  float v = X[i];
  if (RELU_IN) v = fmaxf(v, 0.0f);
  int c = i % M;
  v = v * scale[c] + shift[c];
  if (RELU_OUT) v = fmaxf(v, 0.0f);
  Y[i] = v;
}

// ---------------- final fc (M=1) ----------------

__global__ __launch_bounds__(256) void fc3_k(const float* __restrict__ X,
                                             const float* __restrict__ W,
                                             const float* __restrict__ b,
                                             float* __restrict__ out, int n) {
  int r = blockIdx.x * blockDim.x + threadIdx.x;
  if (r >= n) return;
  const float* xp = X + (size_t)r * 50;
  float acc = b[0];
#pragma unroll
  for (int k = 0; k < 50; ++k) acc += xp[k] * W[k];
  out[r] = acc;
}

// ---------------- launch ----------------

extern "C" void kernel_launch(void* const* d_in, const int* in_sizes, int n_in,
                              void* d_out, int out_size, void* d_ws, size_t ws_size,
                              hipStream_t stream) {
  const float* x = (const float*)d_in[0];
  const int* ei = (const int*)d_in[1];
  const float* conv1_w = (const float*)d_in[2];
  const float* conv1_b = (const float*)d_in[3];
  const float* convs_w = (const float*)d_in[4];
  const float* convs_b = (const float*)d_in[5];
  const float* bn1_g = (const float*)d_in[6];
  const float* bn1_b = (const float*)d_in[7];
  const float* fc1_w = (const float*)d_in[8];
  const float* fc1_b = (const float*)d_in[9];
  const float* bn2_g = (const float*)d_in[10];
  const float* bn2_b = (const float*)d_in[11];
  const float* fc2_w = (const float*)d_in[12];
  const float* fc2_b = (const float*)d_in[13];
  const float* bn3_g = (const float*)d_in[14];
  const float* bn3_b = (const float*)d_in[15];
  const float* fc3_w = (const float*)d_in[16];
  const float* fc3_b = (const float*)d_in[17];

  const int N = in_sizes[0] / 128;
  const int E = in_sizes[1] / 2;
  const int* src = ei;
  const int* dst = ei + E;

  float* ws = (float*)d_ws;
  float* isq = ws;                       // N (deg -> isq in place)
  float* nrm = ws + 50048;               // E
  float* gsum = nrm + E;                 // 128
  float* gsq = gsum + 128;               // 128
  float* scale = gsum + 256;             // 128
  float* shift = gsum + 384;             // 128
  float* buf0 = gsum + 512;              // N*90
  float* buf1 = buf0 + (size_t)N * 90;   // N*90
  float* buf2 = buf1 + (size_t)N * 90;   // N*90

  // graph normalization
  deg_init_k<<<NBLK(N, 256), 256, 0, stream>>>(isq, N);
  deg_edge_k<<<NBLK(E, 256), 256, 0, stream>>>(dst, isq, E);
  isq_k<<<NBLK(N, 256), 256, 0, stream>>>(isq, N);
  norm_k<<<NBLK(E, 256), 256, 0, stream>>>(src, dst, isq, nrm, E);

  const int grows = NBLK(N, 256);
  const int gscat = NBLK(E * 64, 256);

  // layer 1: conv(x,128->90), relu deferred to next gemm's load
  gemm_rows_k<128, 90, false, 1><<<grows, 256, 0, stream>>>(x, conv1_w, conv1_b, isq, buf0, buf1, N);
  scatter_k<90><<<gscat, 256, 0, stream>>>(buf0, src, dst, nrm, buf1, E);

  // layers 2..4: conv(90->90) + relu + bn(bn1)
  for (int i = 0; i < 3; ++i) {
    const float* W = convs_w + (size_t)i * 90 * 90;
    const float* b = convs_b + (size_t)i * 90;
    if (i == 0)
      gemm_rows_k<90, 90, true, 1><<<grows, 256, 0, stream>>>(buf1, W, b, isq, buf0, buf2, N);
    else
      gemm_rows_k<90, 90, false, 1><<<grows, 256, 0, stream>>>(buf1, W, b, isq, buf0, buf2, N);
    scatter_k<90><<<gscat, 256, 0, stream>>>(buf0, src, dst, nrm, buf2, E);
    hipMemsetAsync(gsum, 0, 256 * sizeof(float), stream);
    bn_stats_k<90, true><<<1024, 256, 0, stream>>>(buf2, gsum, gsq, N * 90);
    bn_final_k<90><<<1, 128, 0, stream>>>(gsum, gsq, bn1_g, bn1_b, scale, shift, 1.0f / N);
    bn_apply_k<90, true, false><<<NBLK(N * 90, 256), 256, 0, stream>>>(buf2, scale, shift, buf1, N * 90);
  }

  // fc1: 90->80, bn(bn2), relu
  gemm_rows_k<90, 80, false, 0><<<grows, 256, 0, stream>>>(buf1, fc1_w, fc1_b, nullptr, buf0, nullptr, N);
  hipMemsetAsync(gsum, 0, 256 * sizeof(float), stream);
  bn_stats_k<80, false><<<1024, 256, 0, stream>>>(buf0, gsum, gsq, N * 80);
  bn_final_k<80><<<1, 128, 0, stream>>>(gsum, gsq, bn2_g, bn2_b, scale, shift, 1.0f / N);
  bn_apply_k<80, false, true><<<NBLK(N * 80, 256), 256, 0, stream>>>(buf0, scale, shift, buf2, N * 80);

  // fc2: 80->50, bn(bn3), relu
  gemm_rows_k<80, 50, false, 0><<<grows, 256, 0, stream>>>(buf2, fc2_w, fc2_b, nullptr, buf0, nullptr, N);
  hipMemsetAsync(gsum, 0, 256 * sizeof(float), stream);
  bn_stats_k<50, false><<<1024, 256, 0, stream>>>(buf0, gsum, gsq, N * 50);
  bn_final_k<50><<<1, 128, 0, stream>>>(gsum, gsq, bn3_g, bn3_b, scale, shift, 1.0f / N);
  bn_apply_k<50, false, true><<<NBLK(N * 50, 256), 256, 0, stream>>>(buf0, scale, shift, buf1, N * 50);

  // fc3: 50->1
  fc3_k<<<NBLK(N, 256), 256, 0, stream>>>(buf1, fc3_w, fc3_b, (float*)d_out, N);
}

// Round 2
// 973.775 us; speedup vs baseline: 1.9380x; 1.9380x over previous
//
#include <hip/hip_runtime.h>

#define NBLK(n, b) (((n) + (b) - 1) / (b))

// ---------------- CSR build ----------------

__global__ void count_k(const int* __restrict__ dst, int* __restrict__ cnt, int e) {
  int i = blockIdx.x * blockDim.x + threadIdx.x;
  if (i < e) atomicAdd(&cnt[dst[i]], 1);
}

__global__ void isq_k(const int* __restrict__ cnt, float* __restrict__ isq, int n) {
  int i = blockIdx.x * blockDim.x + threadIdx.x;
  if (i < n) isq[i] = rsqrtf((float)cnt[i] + 1.0f);  // +1 self-loop
}

// single-block exclusive scan: cnt[N] -> rowptr[N+1]
__global__ __launch_bounds__(1024) void scan_k(const int* __restrict__ cnt,
                                               int* __restrict__ rowptr, int n) {
  __shared__ int ls[1024];
  const int t = threadIdx.x;
  const int CS = (n + 1023) >> 10;
  const int lo = t * CS;
  const int hi = min(lo + CS, n);
  int partial = 0;
  for (int i = lo; i < hi; ++i) partial += cnt[i];
  ls[t] = partial;
  __syncthreads();
  // Hillis-Steele inclusive scan
  for (int off = 1; off < 1024; off <<= 1) {
    int v = (t >= off) ? ls[t - off] : 0;
    __syncthreads();
    ls[t] += v;
    __syncthreads();
  }
  int base = ls[t] - partial;  // exclusive
  int run = base;
  for (int i = lo; i < hi; ++i) {
    rowptr[i] = run;
    run += cnt[i];
  }
  if (hi == n && lo < n) rowptr[n] = run;
}

__global__ void fill_k(const int* __restrict__ src, const int* __restrict__ dst,
                       const int* __restrict__ rowptr, int* __restrict__ cursor,
                       int* __restrict__ csr, int e) {
  int i = blockIdx.x * blockDim.x + threadIdx.x;
  if (i >= e) return;
  int d = dst[i];
  int pos = rowptr[d] + atomicAdd(&cursor[d], 1);
  csr[pos] = src[i];
}

// ---------------- dense transform (thread-per-row, W in LDS) ----------------
// XF: 0 = x, 1 = relu(x), 2 = relu(x)*sc+sh, 3 = relu(x*sc+sh)
// EPI: 0 = conv (write acc*isq[row], no bias), 1 = fc (write acc+bias)

template <int K, int M, int MH, int INS, int OUTS, int XF, int EPI>
__global__ __launch_bounds__(256) void gemm_k(
    const float* __restrict__ X, const float* __restrict__ W,
    const float* __restrict__ bias, const float* __restrict__ isq,
    const float* __restrict__ scale, const float* __restrict__ shift,
    float* __restrict__ OUT, int n) {
  __shared__ float Ws[K * MH];
  __shared__ float Sc[(XF >= 2) ? K : 1];
  __shared__ float Sh[(XF >= 2) ? K : 1];
  const int ms = blockIdx.y;
  for (int idx = threadIdx.x; idx < K * MH; idx += 256) {
    int k = idx / MH;
    int m = idx - k * MH;
    Ws[idx] = W[k * M + ms * MH + m];
  }
  if constexpr (XF >= 2) {
    for (int k = threadIdx.x; k < K; k += 256) {
      Sc[k] = scale[k];
      Sh[k] = shift[k];
    }
  }
  __syncthreads();
  int row = blockIdx.x * 256 + threadIdx.x;
  if (row >= n) return;
  float acc[MH];
#pragma unroll
  for (int m = 0; m < MH; ++m) acc[m] = 0.0f;
  const float* xp = X + (size_t)row * INS;
  constexpr int V = ((K % 4) == 0 && (INS % 4) == 0) ? 4 : 2;
  for (int k0 = 0; k0 < K; k0 += V) {
    float xv[V];
    if constexpr (V == 4) {
      float4 t = *reinterpret_cast<const float4*>(xp + k0);
      xv[0] = t.x; xv[1] = t.y; xv[2] = t.z; xv[3] = t.w;
    } else {
      float2 t = *reinterpret_cast<const float2*>(xp + k0);
      xv[0] = t.x; xv[1] = t.y;
    }
#pragma unroll
    for (int j = 0; j < V; ++j) {
      float xval = xv[j];
      if constexpr (XF == 1) xval = fmaxf(xval, 0.0f);
      if constexpr (XF == 2) xval = fmaxf(xval, 0.0f) * Sc[k0 + j] + Sh[k0 + j];
      if constexpr (XF == 3) xval = fmaxf(xval * Sc[k0 + j] + Sh[k0 + j], 0.0f);
      const float* wrow = &Ws[(k0 + j) * MH];
#pragma unroll
      for (int m = 0; m < MH; ++m) acc[m] += xval * wrow[m];
    }
  }
  size_t base = (size_t)row * OUTS + ms * MH;
  if constexpr (EPI == 0) {
    float s = isq[row];
#pragma unroll
    for (int m = 0; m < MH; ++m) OUT[base + m] = acc[m] * s;
  } else {
#pragma unroll
    for (int m = 0; m < MH; ++m) OUT[base + m] = acc[m] + bias[ms * MH + m];
  }
}

// ---------------- CSR gather-reduce: thread per (node, col) ----------------
// H holds Hs = h*isq[src]; out = (Hs[d][c] + sum_edges Hs[src][c]) * isq[d] + bias[c]

template <int M>
__global__ __launch_bounds__(256) void gather_k(
    const float* __restrict__ H, const int* __restrict__ rowptr,
    const int* __restrict__ csr, const float* __restrict__ isq,
    const float* __restrict__ bias, float* __restrict__ A, int n) {
  int gid = blockIdx.x * 256 + threadIdx.x;
  if (gid >= n * M) return;
  int d = gid / M;
  int c = gid - d * M;
  int beg = rowptr[d];
  int end = rowptr[d + 1];
  float a0 = H[(size_t)d * M + c];  // self-loop term (already *isq[d])
  float a1 = 0.0f, a2 = 0.0f, a3 = 0.0f;
  int j = beg;
  for (; j + 4 <= end; j += 4) {
    int s0 = csr[j], s1 = csr[j + 1], s2 = csr[j + 2], s3 = csr[j + 3];
    a0 += H[(size_t)s0 * M + c];
    a1 += H[(size_t)s1 * M + c];
    a2 += H[(size_t)s2 * M + c];
    a3 += H[(size_t)s3 * M + c];
  }
  for (; j < end; ++j) a0 += H[(size_t)csr[j] * M + c];
  A[gid] = ((a0 + a1) + (a2 + a3)) * isq[d] + bias[c];
}

// ---------------- batchnorm ----------------

template <int M, int STRIDE, bool RELU>
__global__ __launch_bounds__(256) void bn_stats_k(const float* __restrict__ X,
                                                  float* __restrict__ gsum,
                                                  float* __restrict__ gsq, int total) {
  __shared__ float ls[4 * M];
  __shared__ float lq[4 * M];
  for (int i = threadIdx.x; i < 4 * M; i += 256) { ls[i] = 0.0f; lq[i] = 0.0f; }
  __syncthreads();
  float* s_ = ls + (threadIdx.x >> 6) * M;
  float* q_ = lq + (threadIdx.x >> 6) * M;
  int stride = gridDim.x * 256;
  for (int i = blockIdx.x * 256 + threadIdx.x; i < total; i += stride) {
    int c = i % STRIDE;
    if (STRIDE == M || c < M) {
      float v = X[i];
      if (RELU) v = fmaxf(v, 0.0f);
      atomicAdd(&s_[c], v);
      atomicAdd(&q_[c], v * v);
    }
  }
  __syncthreads();
  for (int c = threadIdx.x; c < M; c += 256) {
    atomicAdd(&gsum[c], ls[c] + ls[M + c] + ls[2 * M + c] + ls[3 * M + c]);
    atomicAdd(&gsq[c], lq[c] + lq[M + c] + lq[2 * M + c] + lq[3 * M + c]);
  }
}

template <int M>
__global__ void bn_final_k(const float* __restrict__ gsum, const float* __restrict__ gsq,
                           const float* __restrict__ g, const float* __restrict__ b,
                           float* __restrict__ scale, float* __restrict__ shift, float invn) {
  int c = threadIdx.x;
  if (c >= M) return;
  float mu = gsum[c] * invn;
  float var = gsq[c] * invn - mu * mu;
  float r = rsqrtf(var + 1e-5f);
  float sc = g[c] * r;
  scale[c] = sc;
  shift[c] = b[c] - mu * sc;
}

// ---------------- launch ----------------

extern "C" void kernel_launch(void* const* d_in, const int* in_sizes, int n_in,
                              void* d_out, int out_size, void* d_ws, size_t ws_size,
                              hipStream_t stream) {
  const float* x = (const float*)d_in[0];
  const int* ei = (const int*)d_in[1];
  const float* conv1_w = (const float*)d_in[2];
  const float* conv1_b = (const float*)d_in[3];
  const float* convs_w = (const float*)d_in[4];
  const float* convs_b = (const float*)d_in[5];
  const float* bn1_g = (const float*)d_in[6];
  const float* bn1_b = (const float*)d_in[7];
  const float* fc1_w = (const float*)d_in[8];
  const float* fc1_b = (const float*)d_in[9];
  const float* bn2_g = (const float*)d_in[10];
  const float* bn2_b = (const float*)d_in[11];
  const float* fc2_w = (const float*)d_in[12];
  const float* fc2_b = (const float*)d_in[13];
  const float* bn3_g = (const float*)d_in[14];
  const float* bn3_b = (const float*)d_in[15];
  const float* fc3_w = (const float*)d_in[16];
  const float* fc3_b = (const float*)d_in[17];

  const int N = in_sizes[0] / 128;
  const int E = in_sizes[1] / 2;
  const int* src = ei;
  const int* dst = ei + E;

  // workspace layout
  float* ws = (float*)d_ws;
  float* isq = ws;                                  // N floats
  int* rowptr = (int*)(ws + N);                     // N+1 ints
  int* cnt = rowptr + N + 1;                        // N ints
  int* csr = cnt + N;                               // E ints
  float* gsum = (float*)(csr + E);                  // 128
  float* gsq = gsum + 128;                          // 128
  float* scale = gsum + 256;                        // 128
  float* shift = gsum + 384;                        // 128
  float* bufH = gsum + 512;                         // N*90
  float* bufA = bufH + (size_t)N * 90;              // N*90

  // ---- CSR build + norm ----
  hipMemsetAsync(cnt, 0, N * sizeof(int), stream);
  count_k<<<NBLK(E, 256), 256, 0, stream>>>(dst, cnt, E);
  isq_k<<<NBLK(N, 256), 256, 0, stream>>>(cnt, isq, N);
  scan_k<<<1, 1024, 0, stream>>>(cnt, rowptr, N);
  hipMemsetAsync(cnt, 0, N * sizeof(int), stream);
  fill_k<<<NBLK(E, 256), 256, 0, stream>>>(src, dst, rowptr, cnt, csr, E);

  const int grows = NBLK(N, 256);
  const int ggath = NBLK(N * 90, 256);
  const float invn = 1.0f / (float)N;

  // ---- conv1: x[N,128] -> H, gather -> A (raw conv1 out) ----
  gemm_k<128, 90, 45, 128, 90, 0, 0><<<dim3(grows, 2), 256, 0, stream>>>(
      x, conv1_w, nullptr, isq, nullptr, nullptr, bufH, N);
  gather_k<90><<<ggath, 256, 0, stream>>>(bufH, rowptr, csr, isq, conv1_b, bufA, N);

  // ---- conv2..4 ----
  for (int i = 0; i < 3; ++i) {
    const float* W = convs_w + (size_t)i * 90 * 90;
    const float* b = convs_b + (size_t)i * 90;
    if (i == 0)
      gemm_k<90, 90, 45, 90, 90, 1, 0><<<dim3(grows, 2), 256, 0, stream>>>(
          bufA, W, nullptr, isq, nullptr, nullptr, bufH, N);
    else
      gemm_k<90, 90, 45, 90, 90, 2, 0><<<dim3(grows, 2), 256, 0, stream>>>(
          bufA, W, nullptr, isq, scale, shift, bufH, N);
    gather_k<90><<<ggath, 256, 0, stream>>>(bufH, rowptr, csr, isq, b, bufA, N);
    // bn1 on relu(A)
    hipMemsetAsync(gsum, 0, 256 * sizeof(float), stream);
    bn_stats_k<90, 90, true><<<1024, 256, 0, stream>>>(bufA, gsum, gsq, N * 90);
    bn_final_k<90><<<1, 128, 0, stream>>>(gsum, gsq, bn1_g, bn1_b, scale, shift, invn);
  }

  // ---- fc1: A(relu+bn1) -> H [N,80 @ stride 90] ----
  gemm_k<90, 80, 40, 90, 90, 2, 1><<<dim3(grows, 2), 256, 0, stream>>>(
      bufA, fc1_w, fc1_b, nullptr, scale, shift, bufH, N);
  hipMemsetAsync(gsum, 0, 256 * sizeof(float), stream);
  bn_stats_k<80, 90, false><<<1024, 256, 0, stream>>>(bufH, gsum, gsq, N * 90);
  bn_final_k<80><<<1, 128, 0, stream>>>(gsum, gsq, bn2_g, bn2_b, scale, shift, invn);

  // ---- fc2: H(bn2+relu) -> A [N,50 @ stride 90] ----
  gemm_k<80, 50, 25, 90, 90, 3, 1><<<dim3(grows, 2), 256, 0, stream>>>(
      bufH, fc2_w, fc2_b, nullptr, scale, shift, bufA, N);
  hipMemsetAsync(gsum, 0, 256 * sizeof(float), stream);
  bn_stats_k<50, 90, false><<<1024, 256, 0, stream>>>(bufA, gsum, gsq, N * 90);
  bn_final_k<50><<<1, 128, 0, stream>>>(gsum, gsq, bn3_g, bn3_b, scale, shift, invn);

  // ---- fc3: A(bn3+relu) -> out [N,1] ----
  gemm_k<50, 1, 1, 90, 1, 3, 1><<<dim3(grows, 1), 256, 0, stream>>>(
      bufA, fc3_w, fc3_b, nullptr, scale, shift, (float*)d_out, N);
}